// Round 4
// baseline (271.551 us; speedup 1.0000x reference)
//
#include <hip/hip_runtime.h>
#include <cstdint>
#include <cstddef>

#define Bb   2
#define Nn   1024
#define Hh   8
#define DHh  64
#define DMm  512
#define TOPK 102   // int(1024 * (1.0 - 0.9)) == 102

// ---------------------------------------------------------------------------
// C = A @ B_z^T, A [2048][512], B_z [512][512] row-major, C slice z at
// Cb + z*2048*512. Tile 64x64; 4 waves/block, each wave a private K=128 slice
// (no barriers in main loop); 8x8 micro-tile/lane; transposed+swizzled LDS;
// register-prefetched staging; LDS partial reduction at the end.
// ---------------------------------------------------------------------------
__global__ __launch_bounds__(256, 3) void gemm_f32_kw(
    const float* __restrict__ A,
    const float* __restrict__ B0, const float* __restrict__ B1,
    const float* __restrict__ B2, float* __restrict__ Cb) {
  __shared__ float smem[12288];                 // 48 KB
  const int tid  = threadIdx.x;
  const int wv   = tid >> 6;
  const int lane = tid & 63;
  const int bm   = blockIdx.x << 6;
  const int z    = blockIdx.y >> 3;
  const int bn   = (blockIdx.y & 7) << 6;
  const float* __restrict__ Bm = (z == 0) ? B0 : (z == 1) ? B1 : B2;
  float* __restrict__ C = Cb + (size_t)z * (size_t)(Bb * Nn) * DMm;

  float* const Asw = smem + wv * 1024;          // [16][64] this wave
  float* const Bsw = smem + 4096 + wv * 1024;

  const int r  = lane >> 3;     // output row-group 0..7
  const int c  = lane & 7;      // output col-group 0..7
  const int sr = lane >> 2;     // staging row base 0..15
  const int kq = lane & 3;      // staging k-quad 0..3
  const int kw = wv << 7;       // wave K base (0,128,256,384)

  const float* __restrict__ Ag = A  + (size_t)(bm + sr) * DMm + kw + (kq << 2);
  const float* __restrict__ Bg = Bm + (size_t)(bn + sr) * DMm + kw + (kq << 2);

  float acc[8][8] = {};
  float4 pa[4], pb[4];
#pragma unroll
  for (int i = 0; i < 4; ++i) {
    pa[i] = *(const float4*)(Ag + (size_t)(i << 4) * DMm);
    pb[i] = *(const float4*)(Bg + (size_t)(i << 4) * DMm);
  }

  float* aB[8]; float* bB[8];
#pragma unroll
  for (int m = 0; m < 8; ++m) {
    aB[m] = Asw + ((r << 3) ^ (m << 3));
    bB[m] = Bsw + ((c << 3) ^ (m << 3));
  }

  for (int s = 0; s < 8; ++s) {
    // stage regs -> LDS, transposed: element (k,col) at [k*64 + (col ^ ((k&7)<<3))]
#pragma unroll
    for (int i = 0; i < 4; ++i) {
      const int srow = sr + (i << 4);
      const float4 ta = pa[i], tb = pb[i];
      const float va[4] = {ta.x, ta.y, ta.z, ta.w};
      const float vb[4] = {tb.x, tb.y, tb.z, tb.w};
#pragma unroll
      for (int cc = 0; cc < 4; ++cc) {
        const int k   = (kq << 2) + cc;
        const int col = srow ^ ((k & 7) << 3);
        Asw[(k << 6) + col] = va[cc];
        Bsw[(k << 6) + col] = vb[cc];
      }
    }
    if (s < 7) {   // prefetch next step; flies under the 16-kk compute below
      const float* Ag2 = Ag + ((s + 1) << 4);
      const float* Bg2 = Bg + ((s + 1) << 4);
#pragma unroll
      for (int i = 0; i < 4; ++i) {
        pa[i] = *(const float4*)(Ag2 + (size_t)(i << 4) * DMm);
        pb[i] = *(const float4*)(Bg2 + (size_t)(i << 4) * DMm);
      }
    }
#pragma unroll
    for (int kk = 0; kk < 16; ++kk) {
      const int m = kk & 7;
      const float4 a0 = *(const float4*)(aB[m] + (kk << 6));
      const float4 a1 = *(const float4*)(aB[m] + (kk << 6) + 4);
      const float4 b0 = *(const float4*)(bB[m] + (kk << 6));
      const float4 b1 = *(const float4*)(bB[m] + (kk << 6) + 4);
      const float av[8] = {a0.x, a0.y, a0.z, a0.w, a1.x, a1.y, a1.z, a1.w};
      const float bv[8] = {b0.x, b0.y, b0.z, b0.w, b1.x, b1.y, b1.z, b1.w};
#pragma unroll
      for (int i = 0; i < 8; ++i)
#pragma unroll
        for (int j = 0; j < 8; ++j)
          acc[i][j] = fmaf(av[i], bv[j], acc[i][j]);
    }
  }
  __syncthreads();
  if (wv > 0) {       // waves 1..3 publish partials (staging LDS is dead now)
    float* pr = smem + ((wv - 1) << 12) + (r << 9) + (c << 3);
#pragma unroll
    for (int i = 0; i < 8; ++i)
#pragma unroll
      for (int j4 = 0; j4 < 2; ++j4) {
        float4 t;
        t.x = acc[i][(j4 << 2) + 0]; t.y = acc[i][(j4 << 2) + 1];
        t.z = acc[i][(j4 << 2) + 2]; t.w = acc[i][(j4 << 2) + 3];
        *(float4*)(pr + (i << 6) + (j4 << 2)) = t;
      }
  }
  __syncthreads();
  if (wv == 0) {      // wave 0: acc (in regs) + 3 LDS partials -> C
    const float* p1 = smem + (r << 9) + (c << 3);
#pragma unroll
    for (int i = 0; i < 8; ++i) {
#pragma unroll
      for (int j4 = 0; j4 < 2; ++j4) {
        float4 t;
        t.x = acc[i][(j4 << 2) + 0]; t.y = acc[i][(j4 << 2) + 1];
        t.z = acc[i][(j4 << 2) + 2]; t.w = acc[i][(j4 << 2) + 3];
        const float4 q1 = *(const float4*)(p1 +        (i << 6) + (j4 << 2));
        const float4 q2 = *(const float4*)(p1 + 4096 + (i << 6) + (j4 << 2));
        const float4 q3 = *(const float4*)(p1 + 8192 + (i << 6) + (j4 << 2));
        t.x = ((t.x + q1.x) + q2.x) + q3.x;
        t.y = ((t.y + q1.y) + q2.y) + q3.y;
        t.z = ((t.z + q1.z) + q2.z) + q3.z;
        t.w = ((t.w + q1.w) + q2.w) + q3.w;
        *(float4*)(C + (size_t)(bm + (r << 3) + i) * DMm + bn + (c << 3) + (j4 << 2)) = t;
      }
    }
  }
}

// ---------------------------------------------------------------------------
// Hash + norms: one wave per (b,h,n) row. lane = head-dim d.
// ---------------------------------------------------------------------------
__global__ __launch_bounds__(256) void hash_norm_kernel(
    const float* __restrict__ q, const float* __restrict__ k,
    const float* __restrict__ rv,
    uint32_t* __restrict__ qh, uint32_t* __restrict__ kh,
    float* __restrict__ qn, float* __restrict__ kn) {
  const int wid  = threadIdx.x >> 6;
  const int lane = threadIdx.x & 63;
  const int row  = blockIdx.x * 4 + wid;      // b*H*N + h*N + n
  const int n    = row & (Nn - 1);
  const int bh   = row >> 10;
  const int b    = bh >> 3, h = bh & 7;
  const size_t off = (size_t)(b * Nn + n) * DMm + h * DHh + lane;
  const float qd = q[off], kd = k[off];
  float acc[18];
#pragma unroll
  for (int t = 0; t < 8; ++t) {
    float r = rv[t * DHh + lane];
    acc[t]     = qd * r;
    acc[8 + t] = kd * r;
  }
  acc[16] = qd * qd;
  acc[17] = kd * kd;
#pragma unroll
  for (int i = 0; i < 18; ++i) {
#pragma unroll
    for (int s = 1; s < 64; s <<= 1) acc[i] += __shfl_xor(acc[i], s);
  }
  if (lane == 0) {
    uint32_t qb = 0, kb = 0;
#pragma unroll
    for (int t = 0; t < 8; ++t) {
      qb |= (acc[t]     >= 0.f ? 1u : 0u) << t;
      kb |= (acc[8 + t] >= 0.f ? 1u : 0u) << t;
    }
    qh[row] = qb; kh[row] = kb;
    qn[row] = acc[16]; kn[row] = acc[17];
  }
}

// ---------------------------------------------------------------------------
// Attention: one wave per (b,h,n) row, zero block barriers.
// softmax(-acosh(c)) == (1/z)/sum(1/z) with z = c + sqrt(c^2-1): no acosh/exp.
// ---------------------------------------------------------------------------
__global__ __launch_bounds__(256) void attn_wave_kernel(
    const float* __restrict__ q, const float* __restrict__ k,
    const float* __restrict__ v,
    const uint32_t* __restrict__ qh, const uint32_t* __restrict__ kh,
    const float* __restrict__ qn, const float* __restrict__ kn,
    float* __restrict__ out) {
  const int wid  = threadIdx.x >> 6;
  const int lane = threadIdx.x & 63;
  const int row  = blockIdx.x * 4 + wid;      // b*H*N + h*N + n
  const int n    = row & (Nn - 1);
  const int bh   = row >> 10;
  const int b    = bh >> 3, h = bh & 7;

  __shared__ int   sel[4][104];
  __shared__ float dw[4][104];

  const uint32_t myh = qh[row];
  const uint32_t* __restrict__ krh = kh + (bh << 10);

  int m[16];
#pragma unroll
  for (int c = 0; c < 16; ++c)
    m[c] = 8 - __popc(myh ^ krh[(c << 6) + lane]);

  uint32_t p0 = 0, p1 = 0, p2 = 0;
#pragma unroll
  for (int c = 0; c < 16; ++c) {
    uint32_t one = 1u << ((m[c] & 3) << 3);
    int gq = m[c] >> 2;
    p0 += (gq == 0) ? one : 0u;
    p1 += (gq == 1) ? one : 0u;
    p2 += (gq == 2) ? one : 0u;
  }
  uint32_t hr[5];
  hr[0] = (p0 & 0xffu) | (((p0 >> 8) & 0xffu) << 16);
  hr[1] = ((p0 >> 16) & 0xffu) | (((p0 >> 24) & 0xffu) << 16);
  hr[2] = (p1 & 0xffu) | (((p1 >> 8) & 0xffu) << 16);
  hr[3] = ((p1 >> 16) & 0xffu) | (((p1 >> 24) & 0xffu) << 16);
  hr[4] = p2 & 0xffu;
#pragma unroll
  for (int i = 0; i < 5; ++i) {
#pragma unroll
    for (int s = 1; s < 64; s <<= 1) hr[i] += __shfl_xor(hr[i], s);
  }
  int cnt[9];
#pragma unroll
  for (int i = 0; i < 4; ++i) {
    cnt[2 * i]     = hr[i] & 0xffffu;
    cnt[2 * i + 1] = hr[i] >> 16;
  }
  cnt[8] = hr[4] & 0xffffu;

  int thr = 0, R = TOPK, gtc = 0;
  {
    int cum = 0; bool done = false;
#pragma unroll
    for (int mv = 8; mv >= 0; --mv) {
      int cx = cnt[mv];
      if (!done && cum + cx >= TOPK) { thr = mv; R = TOPK - cum; gtc = cum; done = true; }
      if (!done) cum += cx;
    }
  }

  const unsigned long long ltm = (1ULL << lane) - 1ULL;
  int bgt = 0, beq = 0;
#pragma unroll
  for (int c = 0; c < 16; ++c) {
    bool gt = m[c] > thr, eq = m[c] == thr;
    unsigned long long mg = __ballot(gt);
    unsigned long long me = __ballot(eq);
    int rg = bgt + __popcll(mg & ltm);
    int re = beq + __popcll(me & ltm);
    int j = (c << 6) + lane;
    if (gt) sel[wid][rg] = j;
    else if (eq && re < R) sel[wid][gtc + re] = j;
    bgt += __popcll(mg);
    beq += __popcll(me);
  }
  __builtin_amdgcn_wave_barrier();

  const int g  = lane >> 3;
  const int gl = lane & 7;
  const float* __restrict__ qrow = q + (size_t)(b * Nn + n) * DMm + h * DHh + gl * 8;
  const float4 qv0 = *(const float4*)qrow;
  const float4 qv1 = *(const float4*)(qrow + 4);
  const float qnrm = qn[row];
  const float oneq = 1.f - qnrm;
  const float* __restrict__ kbh = k + (size_t)b * Nn * DMm + h * DHh;
  const float* __restrict__ knb = kn + (bh << 10);

#pragma unroll
  for (int it = 0; it < 13; ++it) {
    int s = it * 8 + g;
    bool act = s < TOPK;
    int j = act ? sel[wid][s] : sel[wid][0];
    const float* __restrict__ kr = kbh + (size_t)j * DMm + gl * 8;
    float4 kv0 = *(const float4*)kr;
    float4 kv1 = *(const float4*)(kr + 4);
    float dot = kv0.x * qv0.x;
    dot = fmaf(kv0.y, qv0.y, dot);
    dot = fmaf(kv0.z, qv0.z, dot);
    dot = fmaf(kv0.w, qv0.w, dot);
    dot = fmaf(kv1.x, qv1.x, dot);
    dot = fmaf(kv1.y, qv1.y, dot);
    dot = fmaf(kv1.z, qv1.z, dot);
    dot = fmaf(kv1.w, qv1.w, dot);
    dot += __shfl_xor(dot, 1);
    dot += __shfl_xor(dot, 2);
    dot += __shfl_xor(dot, 4);
    if (gl == 0 && act) dw[wid][s] = dot;
  }
  __builtin_amdgcn_wave_barrier();

  float w0, w1 = 0.f;
  {
    int j0 = sel[wid][lane];
    float dot0 = dw[wid][lane];
    float kn0 = knb[j0];
    float dsq = fmaxf(qnrm + kn0 - 2.f * dot0, 0.f);
    float den = fmaxf(oneq * (1.f - kn0), 1e-6f);
    float cc  = fmaxf(fmaf(2.f * dsq, __builtin_amdgcn_rcpf(den), 1.f), 1.f);
    float zz  = cc + __builtin_amdgcn_sqrtf(fmaf(cc, cc, -1.f));
    w0 = __builtin_amdgcn_rcpf(zz);
  }
  if (lane + 64 < TOPK) {
    int j1 = sel[wid][lane + 64];
    float dot1 = dw[wid][lane + 64];
    float kn1 = knb[j1];
    float dsq = fmaxf(qnrm + kn1 - 2.f * dot1, 0.f);
    float den = fmaxf(oneq * (1.f - kn1), 1e-6f);
    float cc  = fmaxf(fmaf(2.f * dsq, __builtin_amdgcn_rcpf(den), 1.f), 1.f);
    float zz  = cc + __builtin_amdgcn_sqrtf(fmaf(cc, cc, -1.f));
    w1 = __builtin_amdgcn_rcpf(zz);
  }
  float sm = w0 + w1;
#pragma unroll
  for (int s = 1; s < 64; s <<= 1) sm += __shfl_xor(sm, s);
  const float inv = __builtin_amdgcn_rcpf(sm);
  dw[wid][lane] = w0;
  if (lane + 64 < TOPK) dw[wid][lane + 64] = w1;
  __builtin_amdgcn_wave_barrier();

  const float* __restrict__ vbh = v + (size_t)b * Nn * DMm + h * DHh;
  float4 oa0 = {0.f, 0.f, 0.f, 0.f};
  float4 oa1 = {0.f, 0.f, 0.f, 0.f};
#pragma unroll
  for (int it = 0; it < 13; ++it) {
    int s = it * 8 + g;
    if (s < TOPK) {
      int j   = sel[wid][s];
      float w = dw[wid][s];
      const float* __restrict__ vr = vbh + (size_t)j * DMm + gl * 8;
      float4 v0 = *(const float4*)vr;
      float4 v1 = *(const float4*)(vr + 4);
      oa0.x = fmaf(w, v0.x, oa0.x); oa0.y = fmaf(w, v0.y, oa0.y);
      oa0.z = fmaf(w, v0.z, oa0.z); oa0.w = fmaf(w, v0.w, oa0.w);
      oa1.x = fmaf(w, v1.x, oa1.x); oa1.y = fmaf(w, v1.y, oa1.y);
      oa1.z = fmaf(w, v1.z, oa1.z); oa1.w = fmaf(w, v1.w, oa1.w);
    }
  }
#pragma unroll
  for (int s = 8; s < 64; s <<= 1) {
    oa0.x += __shfl_xor(oa0.x, s); oa0.y += __shfl_xor(oa0.y, s);
    oa0.z += __shfl_xor(oa0.z, s); oa0.w += __shfl_xor(oa0.w, s);
    oa1.x += __shfl_xor(oa1.x, s); oa1.y += __shfl_xor(oa1.y, s);
    oa1.z += __shfl_xor(oa1.z, s); oa1.w += __shfl_xor(oa1.w, s);
  }
  if (g == 0) {
    float* __restrict__ orow = out + (size_t)(b * Nn + n) * DMm + h * DHh + gl * 8;
    float4 r0, r1;
    r0.x = oa0.x * inv; r0.y = oa0.y * inv; r0.z = oa0.z * inv; r0.w = oa0.w * inv;
    r1.x = oa1.x * inv; r1.y = oa1.y * inv; r1.z = oa1.z * inv; r1.w = oa1.w * inv;
    *(float4*)orow = r0;
    *(float4*)(orow + 4) = r1;
  }
}

// ---------------------------------------------------------------------------
extern "C" void kernel_launch(void* const* d_in, const int* in_sizes, int n_in,
                              void* d_out, int out_size, void* d_ws, size_t ws_size,
                              hipStream_t stream) {
  const float* x  = (const float*)d_in[0];
  const float* Wq = (const float*)d_in[1];
  const float* Wk = (const float*)d_in[2];
  const float* Wv = (const float*)d_in[3];
  const float* Wo = (const float*)d_in[4];
  const float* rv = (const float*)d_in[5];
  float* outp = (float*)d_out;

  const int M = Bb * Nn;         // 2048 rows
  const int RWS = Bb * Hh * Nn;  // 16384 (b,h,n) rows
  float* q  = (float*)d_ws;
  float* k  = q + (size_t)M * DMm;
  float* v  = k + (size_t)M * DMm;
  float* ao = v + (size_t)M * DMm;
  uint32_t* qh = (uint32_t*)(ao + (size_t)M * DMm);
  uint32_t* kh = qh + RWS;
  float* qn = (float*)(kh + RWS);
  float* kn = qn + RWS;

  dim3 gq(M / 64, 24);           // QKV fused: z = blockIdx.y>>3
  gemm_f32_kw<<<gq, 256, 0, stream>>>(x, Wq, Wk, Wv, q);
  hash_norm_kernel<<<RWS / 4, 256, 0, stream>>>(q, k, rv, qh, kh, qn, kn);
  attn_wave_kernel<<<RWS / 4, 256, 0, stream>>>(q, k, v, qh, kh, qn, kn, ao);
  dim3 go(M / 64, 8);
  gemm_f32_kw<<<go, 256, 0, stream>>>(ao, Wo, Wo, Wo, outp);
}

// Round 6
// 140.756 us; speedup vs baseline: 1.9292x; 1.9292x over previous
//
#include <hip/hip_runtime.h>
#include <cstdint>
#include <cstddef>

#define Bb   2
#define Nn   1024
#define Hh   8
#define DHh  64
#define DMm  512
#define TOPK 102   // int(1024 * (1.0 - 0.9)) == 102

// ---------------------------------------------------------------------------
// C = A @ B_z^T. A [2048][512], B_z [512][512] row-major; C slice z.
// Tile 64x64. 256 threads = 2 pairs x 2 waves; pair p owns K half [p*256,+256).
// Per pair: BK=32 steps, LDS k-major [k][row] stride 68 (pad -> conflict-free),
// micro-tile 8x4 (32 acc regs), reg-prefetched staging. Partials merged in LDS.
// ---------------------------------------------------------------------------
__global__ __launch_bounds__(256) void gemm_f32_ks2(
    const float* __restrict__ A,
    const float* __restrict__ B0, const float* __restrict__ B1,
    const float* __restrict__ B2, float* __restrict__ Cb) {
  __shared__ float smem[8704];                   // 2 pairs * (A 2176 + B 2176)
  const int tid  = threadIdx.x;
  const int pair = tid >> 7;                     // 0,1
  const int tp   = tid & 127;
  const int bm   = blockIdx.x << 6;
  const int z    = blockIdx.y >> 3;
  const int bn   = (blockIdx.y & 7) << 6;
  const float* __restrict__ Bm = (z == 0) ? B0 : (z == 1) ? B1 : B2;
  float* __restrict__ C = Cb + (size_t)z * (size_t)(Bb * Nn) * DMm;

  float* const As = smem + pair * 4352;
  float* const Bs = As + 2176;

  const int ty = tp >> 4;          // 0..7  (rows ty*8..+7)
  const int tx = tp & 15;          // 0..15 (cols tx*4..+3)
  const int sr = tp >> 2;          // staging row 0..31 (and +32)
  const int sk = (tp & 3) << 2;    // staging k offset 0,4,8,12 (and +16)
  const int kb = pair << 8;        // K base 0 / 256

  const float* __restrict__ Ag = A  + (size_t)(bm + sr) * DMm + kb + sk;
  const float* __restrict__ Bg = Bm + (size_t)(bn + sr) * DMm + kb + sk;

  float acc[8][4] = {};
  float4 fa0, fa1, fa2, fa3, fb0, fb1, fb2, fb3;

#define GLOADS(s) do {                                                   \
    const float* a_ = Ag + ((s) << 5);                                   \
    const float* b_ = Bg + ((s) << 5);                                   \
    fa0 = *(const float4*)(a_);                                          \
    fa1 = *(const float4*)(a_ + 16);                                     \
    fa2 = *(const float4*)(a_ + (size_t)32 * DMm);                       \
    fa3 = *(const float4*)(a_ + (size_t)32 * DMm + 16);                  \
    fb0 = *(const float4*)(b_);                                          \
    fb1 = *(const float4*)(b_ + 16);                                     \
    fb2 = *(const float4*)(b_ + (size_t)32 * DMm);                       \
    fb3 = *(const float4*)(b_ + (size_t)32 * DMm + 16);                  \
  } while (0)

#define DSWRITES() do {                                                  \
    const float va0[4] = {fa0.x, fa0.y, fa0.z, fa0.w};                   \
    const float va1[4] = {fa1.x, fa1.y, fa1.z, fa1.w};                   \
    const float va2[4] = {fa2.x, fa2.y, fa2.z, fa2.w};                   \
    const float va3[4] = {fa3.x, fa3.y, fa3.z, fa3.w};                   \
    const float vb0[4] = {fb0.x, fb0.y, fb0.z, fb0.w};                   \
    const float vb1[4] = {fb1.x, fb1.y, fb1.z, fb1.w};                   \
    const float vb2[4] = {fb2.x, fb2.y, fb2.z, fb2.w};                   \
    const float vb3[4] = {fb3.x, fb3.y, fb3.z, fb3.w};                   \
    _Pragma("unroll")                                                    \
    for (int c = 0; c < 4; ++c) {                                        \
      As[(sk + c) * 68 + sr]           = va0[c];                         \
      As[(sk + 16 + c) * 68 + sr]      = va1[c];                         \
      As[(sk + c) * 68 + sr + 32]      = va2[c];                         \
      As[(sk + 16 + c) * 68 + sr + 32] = va3[c];                         \
      Bs[(sk + c) * 68 + sr]           = vb0[c];                         \
      Bs[(sk + 16 + c) * 68 + sr]      = vb1[c];                         \
      Bs[(sk + c) * 68 + sr + 32]      = vb2[c];                         \
      Bs[(sk + 16 + c) * 68 + sr + 32] = vb3[c];                         \
    }                                                                    \
  } while (0)

  GLOADS(0);
  for (int s = 0; s < 8; ++s) {
    DSWRITES();
    __syncthreads();
    if (s < 7) GLOADS(s + 1);          // hidden under the 32-k compute below
#pragma unroll
    for (int kk = 0; kk < 32; ++kk) {
      const float* kr = As + kk * 68 + (ty << 3);
      const float4 a0 = *(const float4*)kr;
      const float4 a1 = *(const float4*)(kr + 4);
      const float4 bv = *(const float4*)(Bs + kk * 68 + (tx << 2));
      const float av[8] = {a0.x, a0.y, a0.z, a0.w, a1.x, a1.y, a1.z, a1.w};
      const float bw[4] = {bv.x, bv.y, bv.z, bv.w};
#pragma unroll
      for (int i = 0; i < 8; ++i)
#pragma unroll
        for (int j = 0; j < 4; ++j)
          acc[i][j] = fmaf(av[i], bw[j], acc[i][j]);
    }
    __syncthreads();
  }

  // merge the two K-halves: pair 1 -> LDS, pair 0 adds + stores
  if (pair) {
#pragma unroll
    for (int i = 0; i < 8; ++i) {
      float4 t;
      t.x = acc[i][0]; t.y = acc[i][1]; t.z = acc[i][2]; t.w = acc[i][3];
      *(float4*)(smem + ((ty << 3) + i) * 64 + (tx << 2)) = t;
    }
  }
  __syncthreads();
  if (!pair) {
#pragma unroll
    for (int i = 0; i < 8; ++i) {
      const float4 p = *(const float4*)(smem + ((ty << 3) + i) * 64 + (tx << 2));
      float4 t;
      t.x = acc[i][0] + p.x; t.y = acc[i][1] + p.y;
      t.z = acc[i][2] + p.z; t.w = acc[i][3] + p.w;
      *(float4*)(C + (size_t)(bm + (ty << 3) + i) * DMm + bn + (tx << 2)) = t;
    }
  }
#undef GLOADS
#undef DSWRITES
}

// ---------------------------------------------------------------------------
// Hash + norms: one wave per (b,h,n) row. lane = head-dim d.
// ---------------------------------------------------------------------------
__global__ __launch_bounds__(256) void hash_norm_kernel(
    const float* __restrict__ q, const float* __restrict__ k,
    const float* __restrict__ rv,
    uint32_t* __restrict__ qh, uint32_t* __restrict__ kh,
    float* __restrict__ qn, float* __restrict__ kn) {
  const int wid  = threadIdx.x >> 6;
  const int lane = threadIdx.x & 63;
  const int row  = blockIdx.x * 4 + wid;      // b*H*N + h*N + n
  const int n    = row & (Nn - 1);
  const int bh   = row >> 10;
  const int b    = bh >> 3, h = bh & 7;
  const size_t off = (size_t)(b * Nn + n) * DMm + h * DHh + lane;
  const float qd = q[off], kd = k[off];
  float acc[18];
#pragma unroll
  for (int t = 0; t < 8; ++t) {
    float r = rv[t * DHh + lane];
    acc[t]     = qd * r;
    acc[8 + t] = kd * r;
  }
  acc[16] = qd * qd;
  acc[17] = kd * kd;
#pragma unroll
  for (int i = 0; i < 18; ++i) {
#pragma unroll
    for (int s = 1; s < 64; s <<= 1) acc[i] += __shfl_xor(acc[i], s);
  }
  if (lane == 0) {
    uint32_t qb = 0, kb = 0;
#pragma unroll
    for (int t = 0; t < 8; ++t) {
      qb |= (acc[t]     >= 0.f ? 1u : 0u) << t;
      kb |= (acc[8 + t] >= 0.f ? 1u : 0u) << t;
    }
    qh[row] = qb; kh[row] = kb;
    qn[row] = acc[16]; kn[row] = acc[17];
  }
}

// ---------------------------------------------------------------------------
// Attention: one wave per (b,h,n) row, zero block barriers.
// softmax(-acosh(c)) == (1/z)/sum(1/z) with z = c + sqrt(c^2-1): no acosh/exp.
// ---------------------------------------------------------------------------
__global__ __launch_bounds__(256) void attn_wave_kernel(
    const float* __restrict__ q, const float* __restrict__ k,
    const float* __restrict__ v,
    const uint32_t* __restrict__ qh, const uint32_t* __restrict__ kh,
    const float* __restrict__ qn, const float* __restrict__ kn,
    float* __restrict__ out) {
  const int wid  = threadIdx.x >> 6;
  const int lane = threadIdx.x & 63;
  const int row  = blockIdx.x * 4 + wid;      // b*H*N + h*N + n
  const int n    = row & (Nn - 1);
  const int bh   = row >> 10;
  const int b    = bh >> 3, h = bh & 7;

  __shared__ int   sel[4][104];
  __shared__ float dw[4][104];

  const uint32_t myh = qh[row];
  const uint32_t* __restrict__ krh = kh + (bh << 10);

  int m[16];
#pragma unroll
  for (int c = 0; c < 16; ++c)
    m[c] = 8 - __popc(myh ^ krh[(c << 6) + lane]);

  uint32_t p0 = 0, p1 = 0, p2 = 0;
#pragma unroll
  for (int c = 0; c < 16; ++c) {
    uint32_t one = 1u << ((m[c] & 3) << 3);
    int gq = m[c] >> 2;
    p0 += (gq == 0) ? one : 0u;
    p1 += (gq == 1) ? one : 0u;
    p2 += (gq == 2) ? one : 0u;
  }
  uint32_t hr[5];
  hr[0] = (p0 & 0xffu) | (((p0 >> 8) & 0xffu) << 16);
  hr[1] = ((p0 >> 16) & 0xffu) | (((p0 >> 24) & 0xffu) << 16);
  hr[2] = (p1 & 0xffu) | (((p1 >> 8) & 0xffu) << 16);
  hr[3] = ((p1 >> 16) & 0xffu) | (((p1 >> 24) & 0xffu) << 16);
  hr[4] = p2 & 0xffu;
#pragma unroll
  for (int i = 0; i < 5; ++i) {
#pragma unroll
    for (int s = 1; s < 64; s <<= 1) hr[i] += __shfl_xor(hr[i], s);
  }
  int cnt[9];
#pragma unroll
  for (int i = 0; i < 4; ++i) {
    cnt[2 * i]     = hr[i] & 0xffffu;
    cnt[2 * i + 1] = hr[i] >> 16;
  }
  cnt[8] = hr[4] & 0xffffu;

  int thr = 0, R = TOPK, gtc = 0;
  {
    int cum = 0; bool done = false;
#pragma unroll
    for (int mv = 8; mv >= 0; --mv) {
      int cx = cnt[mv];
      if (!done && cum + cx >= TOPK) { thr = mv; R = TOPK - cum; gtc = cum; done = true; }
      if (!done) cum += cx;
    }
  }

  const unsigned long long ltm = (1ULL << lane) - 1ULL;
  int bgt = 0, beq = 0;
#pragma unroll
  for (int c = 0; c < 16; ++c) {
    bool gt = m[c] > thr, eq = m[c] == thr;
    unsigned long long mg = __ballot(gt);
    unsigned long long me = __ballot(eq);
    int rg = bgt + __popcll(mg & ltm);
    int re = beq + __popcll(me & ltm);
    int j = (c << 6) + lane;
    if (gt) sel[wid][rg] = j;
    else if (eq && re < R) sel[wid][gtc + re] = j;
    bgt += __popcll(mg);
    beq += __popcll(me);
  }
  __builtin_amdgcn_wave_barrier();

  const int g  = lane >> 3;
  const int gl = lane & 7;
  const float* __restrict__ qrow = q + (size_t)(b * Nn + n) * DMm + h * DHh + gl * 8;
  const float4 qv0 = *(const float4*)qrow;
  const float4 qv1 = *(const float4*)(qrow + 4);
  const float qnrm = qn[row];
  const float oneq = 1.f - qnrm;
  const float* __restrict__ kbh = k + (size_t)b * Nn * DMm + h * DHh;
  const float* __restrict__ knb = kn + (bh << 10);

#pragma unroll
  for (int it = 0; it < 13; ++it) {
    int s = it * 8 + g;
    bool act = s < TOPK;
    int j = act ? sel[wid][s] : sel[wid][0];
    const float* __restrict__ kr = kbh + (size_t)j * DMm + gl * 8;
    float4 kv0 = *(const float4*)kr;
    float4 kv1 = *(const float4*)(kr + 4);
    float dot = kv0.x * qv0.x;
    dot = fmaf(kv0.y, qv0.y, dot);
    dot = fmaf(kv0.z, qv0.z, dot);
    dot = fmaf(kv0.w, qv0.w, dot);
    dot = fmaf(kv1.x, qv1.x, dot);
    dot = fmaf(kv1.y, qv1.y, dot);
    dot = fmaf(kv1.z, qv1.z, dot);
    dot = fmaf(kv1.w, qv1.w, dot);
    dot += __shfl_xor(dot, 1);
    dot += __shfl_xor(dot, 2);
    dot += __shfl_xor(dot, 4);
    if (gl == 0 && act) dw[wid][s] = dot;
  }
  __builtin_amdgcn_wave_barrier();

  float w0, w1 = 0.f;
  {
    int j0 = sel[wid][lane];
    float dot0 = dw[wid][lane];
    float kn0 = knb[j0];
    float dsq = fmaxf(qnrm + kn0 - 2.f * dot0, 0.f);
    float den = fmaxf(oneq * (1.f - kn0), 1e-6f);
    float cc  = fmaxf(fmaf(2.f * dsq, __builtin_amdgcn_rcpf(den), 1.f), 1.f);
    float zz  = cc + __builtin_amdgcn_sqrtf(fmaf(cc, cc, -1.f));
    w0 = __builtin_amdgcn_rcpf(zz);
  }
  if (lane + 64 < TOPK) {
    int j1 = sel[wid][lane + 64];
    float dot1 = dw[wid][lane + 64];
    float kn1 = knb[j1];
    float dsq = fmaxf(qnrm + kn1 - 2.f * dot1, 0.f);
    float den = fmaxf(oneq * (1.f - kn1), 1e-6f);
    float cc  = fmaxf(fmaf(2.f * dsq, __builtin_amdgcn_rcpf(den), 1.f), 1.f);
    float zz  = cc + __builtin_amdgcn_sqrtf(fmaf(cc, cc, -1.f));
    w1 = __builtin_amdgcn_rcpf(zz);
  }
  float sm = w0 + w1;
#pragma unroll
  for (int s = 1; s < 64; s <<= 1) sm += __shfl_xor(sm, s);
  const float inv = __builtin_amdgcn_rcpf(sm);
  dw[wid][lane] = w0;
  if (lane + 64 < TOPK) dw[wid][lane + 64] = w1;
  __builtin_amdgcn_wave_barrier();

  const float* __restrict__ vbh = v + (size_t)b * Nn * DMm + h * DHh;
  float4 oa0 = {0.f, 0.f, 0.f, 0.f};
  float4 oa1 = {0.f, 0.f, 0.f, 0.f};
#pragma unroll
  for (int it = 0; it < 13; ++it) {
    int s = it * 8 + g;
    if (s < TOPK) {
      int j   = sel[wid][s];
      float w = dw[wid][s];
      const float* __restrict__ vr = vbh + (size_t)j * DMm + gl * 8;
      float4 v0 = *(const float4*)vr;
      float4 v1 = *(const float4*)(vr + 4);
      oa0.x = fmaf(w, v0.x, oa0.x); oa0.y = fmaf(w, v0.y, oa0.y);
      oa0.z = fmaf(w, v0.z, oa0.z); oa0.w = fmaf(w, v0.w, oa0.w);
      oa1.x = fmaf(w, v1.x, oa1.x); oa1.y = fmaf(w, v1.y, oa1.y);
      oa1.z = fmaf(w, v1.z, oa1.z); oa1.w = fmaf(w, v1.w, oa1.w);
    }
  }
#pragma unroll
  for (int s = 8; s < 64; s <<= 1) {
    oa0.x += __shfl_xor(oa0.x, s); oa0.y += __shfl_xor(oa0.y, s);
    oa0.z += __shfl_xor(oa0.z, s); oa0.w += __shfl_xor(oa0.w, s);
    oa1.x += __shfl_xor(oa1.x, s); oa1.y += __shfl_xor(oa1.y, s);
    oa1.z += __shfl_xor(oa1.z, s); oa1.w += __shfl_xor(oa1.w, s);
  }
  if (g == 0) {
    float* __restrict__ orow = out + (size_t)(b * Nn + n) * DMm + h * DHh + gl * 8;
    float4 r0, r1;
    r0.x = oa0.x * inv; r0.y = oa0.y * inv; r0.z = oa0.z * inv; r0.w = oa0.w * inv;
    r1.x = oa1.x * inv; r1.y = oa1.y * inv; r1.z = oa1.z * inv; r1.w = oa1.w * inv;
    *(float4*)orow = r0;
    *(float4*)(orow + 4) = r1;
  }
}

// ---------------------------------------------------------------------------
extern "C" void kernel_launch(void* const* d_in, const int* in_sizes, int n_in,
                              void* d_out, int out_size, void* d_ws, size_t ws_size,
                              hipStream_t stream) {
  const float* x  = (const float*)d_in[0];
  const float* Wq = (const float*)d_in[1];
  const float* Wk = (const float*)d_in[2];
  const float* Wv = (const float*)d_in[3];
  const float* Wo = (const float*)d_in[4];
  const float* rv = (const float*)d_in[5];
  float* outp = (float*)d_out;

  const int M = Bb * Nn;         // 2048 rows
  const int RWS = Bb * Hh * Nn;  // 16384 (b,h,n) rows
  float* q  = (float*)d_ws;
  float* k  = q + (size_t)M * DMm;
  float* v  = k + (size_t)M * DMm;
  float* ao = v + (size_t)M * DMm;
  uint32_t* qh = (uint32_t*)(ao + (size_t)M * DMm);
  uint32_t* kh = qh + RWS;
  float* qn = (float*)(kh + RWS);
  float* kn = qn + RWS;

  dim3 gq(M / 64, 24);           // QKV fused: z = blockIdx.y>>3
  gemm_f32_ks2<<<gq, 256, 0, stream>>>(x, Wq, Wk, Wv, q);
  hash_norm_kernel<<<RWS / 4, 256, 0, stream>>>(q, k, rv, qh, kh, qn, kn);
  attn_wave_kernel<<<RWS / 4, 256, 0, stream>>>(q, k, v, qh, kh, qn, kn, ao);
  dim3 go(M / 64, 8);
  gemm_f32_ks2<<<go, 256, 0, stream>>>(ao, Wo, Wo, Wo, outp);
}

// Round 7
// 134.621 us; speedup vs baseline: 2.0171x; 1.0456x over previous
//
#include <hip/hip_runtime.h>
#include <cstdint>
#include <cstddef>

#define Bb   2
#define Nn   1024
#define Hh   8
#define DHh  64
#define DMm  512
#define TOPK 102   // int(1024 * (1.0 - 0.9)) == 102

// ---------------------------------------------------------------------------
// C = A @ B_z^T. A [2048][512], B_z [512][512] row-major; C slice z.
// Tile 64x64, 4 waves; wave w owns private K slice [w*128, +128) -> NO
// barriers in the main loop. Micro-tile 8x8 (64 acc regs, 64 FMA : 4 ds_read
// -> 2x better FMA:LDS ratio than 8x4). LDS k-major [k][row] stride 68.
// Stage loop NOT unrolled (pins VGPR; latency hidden by 3 blocks/CU TLP).
// Partials merged once via LDS (structure proven correct in round 4).
// ---------------------------------------------------------------------------
__global__ __launch_bounds__(256) void gemm_f32_k4(
    const float* __restrict__ A,
    const float* __restrict__ B0, const float* __restrict__ B1,
    const float* __restrict__ B2, float* __restrict__ Cb) {
  __shared__ float smem[12288];        // staging: 4w x 2176 = 8704; merge: 3 x 4096
  const int tid  = threadIdx.x;
  const int wv   = tid >> 6;
  const int lane = tid & 63;
  const int bm   = blockIdx.x << 6;
  const int z    = blockIdx.y >> 3;
  const int bn   = (blockIdx.y & 7) << 6;
  const float* __restrict__ Bm = (z == 0) ? B0 : (z == 1) ? B1 : B2;
  float* __restrict__ C = Cb + (size_t)z * (size_t)(Bb * Nn) * DMm;

  float* const As = smem + wv * 2176;  // [16][68]
  float* const Bs = As + 1088;

  const int rg = lane >> 3;            // output rows bm + rg*8 .. +7
  const int cg = lane & 7;             // output cols bn + cg*8 .. +7
  const int sr = lane >> 2;            // staging row 0..15 (+16/32/48)
  const int sk = (lane & 3) << 2;      // staging k offset 0,4,8,12
  const int kb = wv << 7;              // wave K base 0/128/256/384

  const float* __restrict__ Ag = A  + (size_t)(bm + sr) * DMm + kb + sk;
  const float* __restrict__ Bg = Bm + (size_t)(bn + sr) * DMm + kb + sk;

  float acc[8][8] = {};

#pragma unroll 1
  for (int s = 0; s < 8; ++s) {
    const int ko = s << 4;
    {  // stage A (16 B/lane global, transposed scalar LDS writes, 2-way free)
      float4 t0 = *(const float4*)(Ag + ko);
      float4 t1 = *(const float4*)(Ag + ko + (size_t)16 * DMm);
      float4 t2 = *(const float4*)(Ag + ko + (size_t)32 * DMm);
      float4 t3 = *(const float4*)(Ag + ko + (size_t)48 * DMm);
      const float w0[4] = {t0.x, t0.y, t0.z, t0.w};
      const float w1[4] = {t1.x, t1.y, t1.z, t1.w};
      const float w2[4] = {t2.x, t2.y, t2.z, t2.w};
      const float w3[4] = {t3.x, t3.y, t3.z, t3.w};
#pragma unroll
      for (int c = 0; c < 4; ++c) {
        float* p = As + (sk + c) * 68 + sr;
        p[0]  = w0[c];
        p[16] = w1[c];
        p[32] = w2[c];
        p[48] = w3[c];
      }
    }
    {  // stage B
      float4 t0 = *(const float4*)(Bg + ko);
      float4 t1 = *(const float4*)(Bg + ko + (size_t)16 * DMm);
      float4 t2 = *(const float4*)(Bg + ko + (size_t)32 * DMm);
      float4 t3 = *(const float4*)(Bg + ko + (size_t)48 * DMm);
      const float w0[4] = {t0.x, t0.y, t0.z, t0.w};
      const float w1[4] = {t1.x, t1.y, t1.z, t1.w};
      const float w2[4] = {t2.x, t2.y, t2.z, t2.w};
      const float w3[4] = {t3.x, t3.y, t3.z, t3.w};
#pragma unroll
      for (int c = 0; c < 4; ++c) {
        float* p = Bs + (sk + c) * 68 + sr;
        p[0]  = w0[c];
        p[16] = w1[c];
        p[32] = w2[c];
        p[48] = w3[c];
      }
    }
    // wave-internal ds_write -> ds_read ordering handled by lgkmcnt (no barrier)
#pragma unroll
    for (int kk = 0; kk < 16; ++kk) {
      const float* pa = As + kk * 68 + (rg << 3);
      const float* pb = Bs + kk * 68 + (cg << 3);
      const float4 a0 = *(const float4*)pa;
      const float4 a1 = *(const float4*)(pa + 4);
      const float4 b0 = *(const float4*)pb;
      const float4 b1 = *(const float4*)(pb + 4);
      const float av[8] = {a0.x, a0.y, a0.z, a0.w, a1.x, a1.y, a1.z, a1.w};
      const float bw[8] = {b0.x, b0.y, b0.z, b0.w, b1.x, b1.y, b1.z, b1.w};
#pragma unroll
      for (int i = 0; i < 8; ++i)
#pragma unroll
        for (int j = 0; j < 8; ++j)
          acc[i][j] = fmaf(av[i], bw[j], acc[i][j]);
    }
  }

  // merge K-slices: waves 1..3 publish partials, wave 0 reduces + stores
  __syncthreads();
  if (wv > 0) {
    float* pr = smem + ((wv - 1) << 12) + (rg << 9) + (cg << 3);
#pragma unroll
    for (int i = 0; i < 8; ++i) {
      float4 t0, t1;
      t0.x = acc[i][0]; t0.y = acc[i][1]; t0.z = acc[i][2]; t0.w = acc[i][3];
      t1.x = acc[i][4]; t1.y = acc[i][5]; t1.z = acc[i][6]; t1.w = acc[i][7];
      *(float4*)(pr + (i << 6))     = t0;
      *(float4*)(pr + (i << 6) + 4) = t1;
    }
  }
  __syncthreads();
  if (wv == 0) {
    const float* p1 = smem + (rg << 9) + (cg << 3);
#pragma unroll
    for (int i = 0; i < 8; ++i) {
#pragma unroll
      for (int h4 = 0; h4 < 2; ++h4) {
        float4 t;
        t.x = acc[i][h4 * 4 + 0]; t.y = acc[i][h4 * 4 + 1];
        t.z = acc[i][h4 * 4 + 2]; t.w = acc[i][h4 * 4 + 3];
        const float4 q1 = *(const float4*)(p1 +        (i << 6) + h4 * 4);
        const float4 q2 = *(const float4*)(p1 + 4096 + (i << 6) + h4 * 4);
        const float4 q3 = *(const float4*)(p1 + 8192 + (i << 6) + h4 * 4);
        t.x = ((t.x + q1.x) + q2.x) + q3.x;
        t.y = ((t.y + q1.y) + q2.y) + q3.y;
        t.z = ((t.z + q1.z) + q2.z) + q3.z;
        t.w = ((t.w + q1.w) + q2.w) + q3.w;
        *(float4*)(C + (size_t)(bm + (rg << 3) + i) * DMm + bn + (cg << 3) + h4 * 4) = t;
      }
    }
  }
}

// ---------------------------------------------------------------------------
// Hash + norms: one wave per (b,h,n) row. lane = head-dim d.
// ---------------------------------------------------------------------------
__global__ __launch_bounds__(256) void hash_norm_kernel(
    const float* __restrict__ q, const float* __restrict__ k,
    const float* __restrict__ rv,
    uint32_t* __restrict__ qh, uint32_t* __restrict__ kh,
    float* __restrict__ qn, float* __restrict__ kn) {
  const int wid  = threadIdx.x >> 6;
  const int lane = threadIdx.x & 63;
  const int row  = blockIdx.x * 4 + wid;      // b*H*N + h*N + n
  const int n    = row & (Nn - 1);
  const int bh   = row >> 10;
  const int b    = bh >> 3, h = bh & 7;
  const size_t off = (size_t)(b * Nn + n) * DMm + h * DHh + lane;
  const float qd = q[off], kd = k[off];
  float acc[18];
#pragma unroll
  for (int t = 0; t < 8; ++t) {
    float r = rv[t * DHh + lane];
    acc[t]     = qd * r;
    acc[8 + t] = kd * r;
  }
  acc[16] = qd * qd;
  acc[17] = kd * kd;
#pragma unroll
  for (int i = 0; i < 18; ++i) {
#pragma unroll
    for (int s = 1; s < 64; s <<= 1) acc[i] += __shfl_xor(acc[i], s);
  }
  if (lane == 0) {
    uint32_t qb = 0, kb = 0;
#pragma unroll
    for (int t = 0; t < 8; ++t) {
      qb |= (acc[t]     >= 0.f ? 1u : 0u) << t;
      kb |= (acc[8 + t] >= 0.f ? 1u : 0u) << t;
    }
    qh[row] = qb; kh[row] = kb;
    qn[row] = acc[16]; kn[row] = acc[17];
  }
}

// ---------------------------------------------------------------------------
// Attention: one wave per (b,h,n) row, zero block barriers.
// softmax(-acosh(c)) == (1/z)/sum(1/z) with z = c + sqrt(c^2-1): no acosh/exp.
// ---------------------------------------------------------------------------
__global__ __launch_bounds__(256) void attn_wave_kernel(
    const float* __restrict__ q, const float* __restrict__ k,
    const float* __restrict__ v,
    const uint32_t* __restrict__ qh, const uint32_t* __restrict__ kh,
    const float* __restrict__ qn, const float* __restrict__ kn,
    float* __restrict__ out) {
  const int wid  = threadIdx.x >> 6;
  const int lane = threadIdx.x & 63;
  const int row  = blockIdx.x * 4 + wid;      // b*H*N + h*N + n
  const int n    = row & (Nn - 1);
  const int bh   = row >> 10;
  const int b    = bh >> 3, h = bh & 7;

  __shared__ int   sel[4][104];
  __shared__ float dw[4][104];

  const uint32_t myh = qh[row];
  const uint32_t* __restrict__ krh = kh + (bh << 10);

  int m[16];
#pragma unroll
  for (int c = 0; c < 16; ++c)
    m[c] = 8 - __popc(myh ^ krh[(c << 6) + lane]);

  uint32_t p0 = 0, p1 = 0, p2 = 0;
#pragma unroll
  for (int c = 0; c < 16; ++c) {
    uint32_t one = 1u << ((m[c] & 3) << 3);
    int gq = m[c] >> 2;
    p0 += (gq == 0) ? one : 0u;
    p1 += (gq == 1) ? one : 0u;
    p2 += (gq == 2) ? one : 0u;
  }
  uint32_t hr[5];
  hr[0] = (p0 & 0xffu) | (((p0 >> 8) & 0xffu) << 16);
  hr[1] = ((p0 >> 16) & 0xffu) | (((p0 >> 24) & 0xffu) << 16);
  hr[2] = (p1 & 0xffu) | (((p1 >> 8) & 0xffu) << 16);
  hr[3] = ((p1 >> 16) & 0xffu) | (((p1 >> 24) & 0xffu) << 16);
  hr[4] = p2 & 0xffu;
#pragma unroll
  for (int i = 0; i < 5; ++i) {
#pragma unroll
    for (int s = 1; s < 64; s <<= 1) hr[i] += __shfl_xor(hr[i], s);
  }
  int cnt[9];
#pragma unroll
  for (int i = 0; i < 4; ++i) {
    cnt[2 * i]     = hr[i] & 0xffffu;
    cnt[2 * i + 1] = hr[i] >> 16;
  }
  cnt[8] = hr[4] & 0xffffu;

  int thr = 0, R = TOPK, gtc = 0;
  {
    int cum = 0; bool done = false;
#pragma unroll
    for (int mv = 8; mv >= 0; --mv) {
      int cx = cnt[mv];
      if (!done && cum + cx >= TOPK) { thr = mv; R = TOPK - cum; gtc = cum; done = true; }
      if (!done) cum += cx;
    }
  }

  const unsigned long long ltm = (1ULL << lane) - 1ULL;
  int bgt = 0, beq = 0;
#pragma unroll
  for (int c = 0; c < 16; ++c) {
    bool gt = m[c] > thr, eq = m[c] == thr;
    unsigned long long mg = __ballot(gt);
    unsigned long long me = __ballot(eq);
    int rg = bgt + __popcll(mg & ltm);
    int re = beq + __popcll(me & ltm);
    int j = (c << 6) + lane;
    if (gt) sel[wid][rg] = j;
    else if (eq && re < R) sel[wid][gtc + re] = j;
    bgt += __popcll(mg);
    beq += __popcll(me);
  }
  __builtin_amdgcn_wave_barrier();

  const int g  = lane >> 3;
  const int gl = lane & 7;
  const float* __restrict__ qrow = q + (size_t)(b * Nn + n) * DMm + h * DHh + gl * 8;
  const float4 qv0 = *(const float4*)qrow;
  const float4 qv1 = *(const float4*)(qrow + 4);
  const float qnrm = qn[row];
  const float oneq = 1.f - qnrm;
  const float* __restrict__ kbh = k + (size_t)b * Nn * DMm + h * DHh;
  const float* __restrict__ knb = kn + (bh << 10);

#pragma unroll
  for (int it = 0; it < 13; ++it) {
    int s = it * 8 + g;
    bool act = s < TOPK;
    int j = act ? sel[wid][s] : sel[wid][0];
    const float* __restrict__ kr = kbh + (size_t)j * DMm + gl * 8;
    float4 kv0 = *(const float4*)kr;
    float4 kv1 = *(const float4*)(kr + 4);
    float dot = kv0.x * qv0.x;
    dot = fmaf(kv0.y, qv0.y, dot);
    dot = fmaf(kv0.z, qv0.z, dot);
    dot = fmaf(kv0.w, qv0.w, dot);
    dot = fmaf(kv1.x, qv1.x, dot);
    dot = fmaf(kv1.y, qv1.y, dot);
    dot = fmaf(kv1.z, qv1.z, dot);
    dot = fmaf(kv1.w, qv1.w, dot);
    dot += __shfl_xor(dot, 1);
    dot += __shfl_xor(dot, 2);
    dot += __shfl_xor(dot, 4);
    if (gl == 0 && act) dw[wid][s] = dot;
  }
  __builtin_amdgcn_wave_barrier();

  float w0, w1 = 0.f;
  {
    int j0 = sel[wid][lane];
    float dot0 = dw[wid][lane];
    float kn0 = knb[j0];
    float dsq = fmaxf(qnrm + kn0 - 2.f * dot0, 0.f);
    float den = fmaxf(oneq * (1.f - kn0), 1e-6f);
    float cc  = fmaxf(fmaf(2.f * dsq, __builtin_amdgcn_rcpf(den), 1.f), 1.f);
    float zz  = cc + __builtin_amdgcn_sqrtf(fmaf(cc, cc, -1.f));
    w0 = __builtin_amdgcn_rcpf(zz);
  }
  if (lane + 64 < TOPK) {
    int j1 = sel[wid][lane + 64];
    float dot1 = dw[wid][lane + 64];
    float kn1 = knb[j1];
    float dsq = fmaxf(qnrm + kn1 - 2.f * dot1, 0.f);
    float den = fmaxf(oneq * (1.f - kn1), 1e-6f);
    float cc  = fmaxf(fmaf(2.f * dsq, __builtin_amdgcn_rcpf(den), 1.f), 1.f);
    float zz  = cc + __builtin_amdgcn_sqrtf(fmaf(cc, cc, -1.f));
    w1 = __builtin_amdgcn_rcpf(zz);
  }
  float sm = w0 + w1;
#pragma unroll
  for (int s = 1; s < 64; s <<= 1) sm += __shfl_xor(sm, s);
  const float inv = __builtin_amdgcn_rcpf(sm);
  dw[wid][lane] = w0;
  if (lane + 64 < TOPK) dw[wid][lane + 64] = w1;
  __builtin_amdgcn_wave_barrier();

  const float* __restrict__ vbh = v + (size_t)b * Nn * DMm + h * DHh;
  float4 oa0 = {0.f, 0.f, 0.f, 0.f};
  float4 oa1 = {0.f, 0.f, 0.f, 0.f};
#pragma unroll
  for (int it = 0; it < 13; ++it) {
    int s = it * 8 + g;
    if (s < TOPK) {
      int j   = sel[wid][s];
      float w = dw[wid][s];
      const float* __restrict__ vr = vbh + (size_t)j * DMm + gl * 8;
      float4 v0 = *(const float4*)vr;
      float4 v1 = *(const float4*)(vr + 4);
      oa0.x = fmaf(w, v0.x, oa0.x); oa0.y = fmaf(w, v0.y, oa0.y);
      oa0.z = fmaf(w, v0.z, oa0.z); oa0.w = fmaf(w, v0.w, oa0.w);
      oa1.x = fmaf(w, v1.x, oa1.x); oa1.y = fmaf(w, v1.y, oa1.y);
      oa1.z = fmaf(w, v1.z, oa1.z); oa1.w = fmaf(w, v1.w, oa1.w);
    }
  }
#pragma unroll
  for (int s = 8; s < 64; s <<= 1) {
    oa0.x += __shfl_xor(oa0.x, s); oa0.y += __shfl_xor(oa0.y, s);
    oa0.z += __shfl_xor(oa0.z, s); oa0.w += __shfl_xor(oa0.w, s);
    oa1.x += __shfl_xor(oa1.x, s); oa1.y += __shfl_xor(oa1.y, s);
    oa1.z += __shfl_xor(oa1.z, s); oa1.w += __shfl_xor(oa1.w, s);
  }
  if (g == 0) {
    float* __restrict__ orow = out + (size_t)(b * Nn + n) * DMm + h * DHh + gl * 8;
    float4 r0, r1;
    r0.x = oa0.x * inv; r0.y = oa0.y * inv; r0.z = oa0.z * inv; r0.w = oa0.w * inv;
    r1.x = oa1.x * inv; r1.y = oa1.y * inv; r1.z = oa1.z * inv; r1.w = oa1.w * inv;
    *(float4*)orow = r0;
    *(float4*)(orow + 4) = r1;
  }
}

// ---------------------------------------------------------------------------
extern "C" void kernel_launch(void* const* d_in, const int* in_sizes, int n_in,
                              void* d_out, int out_size, void* d_ws, size_t ws_size,
                              hipStream_t stream) {
  const float* x  = (const float*)d_in[0];
  const float* Wq = (const float*)d_in[1];
  const float* Wk = (const float*)d_in[2];
  const float* Wv = (const float*)d_in[3];
  const float* Wo = (const float*)d_in[4];
  const float* rv = (const float*)d_in[5];
  float* outp = (float*)d_out;

  const int M = Bb * Nn;         // 2048 rows
  const int RWS = Bb * Hh * Nn;  // 16384 (b,h,n) rows
  float* q  = (float*)d_ws;
  float* k  = q + (size_t)M * DMm;
  float* v  = k + (size_t)M * DMm;
  float* ao = v + (size_t)M * DMm;
  uint32_t* qh = (uint32_t*)(ao + (size_t)M * DMm);
  uint32_t* kh = qh + RWS;
  float* qn = (float*)(kh + RWS);
  float* kn = qn + RWS;

  dim3 gq(M / 64, 24);           // QKV fused: z = blockIdx.y>>3
  gemm_f32_k4<<<gq, 256, 0, stream>>>(x, Wq, Wk, Wv, q);
  hash_norm_kernel<<<RWS / 4, 256, 0, stream>>>(q, k, rv, qh, kh, qn, kn);
  attn_wave_kernel<<<RWS / 4, 256, 0, stream>>>(q, k, v, qh, kh, qn, kn, ao);
  dim3 go(M / 64, 8);
  gemm_f32_k4<<<go, 256, 0, stream>>>(ao, Wo, Wo, Wo, outp);
}